// Round 11
// baseline (104.054 us; speedup 1.0000x reference)
//
#include <hip/hip_runtime.h>

#define DEV __device__ __forceinline__

typedef _Float16 half8 __attribute__((ext_vector_type(8)));
typedef _Float16 half2v __attribute__((ext_vector_type(2)));
typedef float f32x16 __attribute__((ext_vector_type(16)));
typedef int int4v __attribute__((ext_vector_type(4)));

DEV f32x16 mfma16(half8 a, half8 b, f32x16 c) {
    return __builtin_amdgcn_mfma_f32_32x32x16_f16(a, b, c, 0, 0, 0);
}
DEV half8 h8(int4v v) { return __builtin_bit_cast(half8, v); }
DEV half8 ldh8(const _Float16* p) { return *(const half8*)p; }
DEV int pkrtz(float a, float b) {
    auto t = __builtin_amdgcn_cvt_pkrtz(a, b);
    return __builtin_bit_cast(int, t);
}
// pack two f32 -> f16x2 (RTZ), add packed f16 bias, then packed relu: 3 VALU per 2 values
DEV int pk_bias_relu(float a, float b, int biaspk) {
    int p = pkrtz(a, b);
    half2v s = __builtin_bit_cast(half2v, p) + __builtin_bit_cast(half2v, biaspk); // v_pk_add_f16
    half2v z = {(_Float16)0.f, (_Float16)0.f};
    s = __builtin_elementwise_max(s, z);   // v_pk_max_f16
    return __builtin_bit_cast(int, s);
}
DEV int pk_relu(float a, float b) {
    int p = pkrtz(a, b);
    half2v s = __builtin_bit_cast(half2v, p);
    half2v z = {(_Float16)0.f, (_Float16)0.f};
    s = __builtin_elementwise_max(s, z);
    return __builtin_bit_cast(int, s);
}
// v_permlane32_swap_b32: a[32..63] <-> b[0..31]
DEV void plswap(int& a, int& b) {
    asm("v_permlane32_swap_b32 %0, %1" : "+v"(a), "+v"(b));
}

struct Frags { int4v c[4]; };  // activation B-fragments, K=64 (4 chunks of 16)

// cross-half swap section: P0 (feats 0-31) -> B.c[0..1], P1 (feats 32-63) -> B.c[2..3]
DEV void swap_pack(const int* P0, const int* P1, Frags& B) {
#pragma unroll
    for (int kk = 0; kk < 4; ++kk) {
        const int* Pm = (kk < 2) ? P0 : P1;
        int idx = 4 * (kk & 1);
        int a0 = Pm[idx + 0], b0 = Pm[idx + 2];
        int a1 = Pm[idx + 1], b1 = Pm[idx + 3];
        plswap(a0, b0);
        plswap(a1, b1);
        int4v nb; nb[0] = a0; nb[1] = a1; nb[2] = b0; nb[3] = b1;
        B.c[kk] = nb;
    }
}

// hidden-layer repack: pack + packed-f16 bias add + relu + swap. Bq[0..1]=m0 bias, Bq[2..3]=m1
DEV void repack_b(const f32x16& C0, const f32x16& C1, const int4v* Bq, Frags& B) {
    int P0[8], P1[8];
#pragma unroll
    for (int q = 0; q < 8; ++q) {
        int b0 = (q < 4) ? Bq[0][q & 3] : Bq[1][q & 3];
        int b1 = (q < 4) ? Bq[2][q & 3] : Bq[3][q & 3];
        P0[q] = pk_bias_relu(C0[2*q], C0[2*q+1], b0);
        P1[q] = pk_bias_relu(C1[2*q], C1[2*q+1], b1);
    }
    swap_pack(P0, P1, B);
}
// input-layer repack: bias already embedded (x k=28 slot), no add
DEV void repack_nb(const f32x16& C0, const f32x16& C1, Frags& B) {
    int P0[8], P1[8];
#pragma unroll
    for (int q = 0; q < 8; ++q) {
        P0[q] = pk_relu(C0[2*q], C0[2*q+1]);
        P1[q] = pk_relu(C1[2*q], C1[2*q+1]);
    }
    swap_pack(P0, P1, B);
}

// 8 ds_read_b128: one hidden layer's A-fragments (4 chunks x 2 m-halves)
DEV void loadA4(const _Float16* base, int lam, half8* A0, half8* A1) {
    const _Float16* p0 = base + lam * 8;
    const _Float16* p1 = base + 2048 + lam * 8;
#pragma unroll
    for (int kk = 0; kk < 4; ++kk) {
        A0[kk] = ldh8(p0 + kk * 512);
        A1[kk] = ldh8(p1 + kk * 512);
    }
}
// 4 ds_read_b128: packed bias for one layer (m0,m1), lane's own h-group (broadcast)
DEV void loadBias(const int* biasPk, int l, int h, int4v* Bq) {
    const int* p = biasPk + l * 32 + h * 8;
    Bq[0] = *(const int4v*)(p);
    Bq[1] = *(const int4v*)(p + 4);
    Bq[2] = *(const int4v*)(p + 16);
    Bq[3] = *(const int4v*)(p + 20);
}

// hidden layer burst: 8 MFMA, C-init from Z (zero)
DEV void mfma_hid8(const half8* A0, const half8* A1, const Frags& Bx, const f32x16& Z,
                   f32x16& C0, f32x16& C1) {
    C0 = mfma16(A0[0], h8(Bx.c[0]), Z);
    C1 = mfma16(A1[0], h8(Bx.c[0]), Z);
#pragma unroll
    for (int kk = 1; kk < 4; ++kk) {
        half8 b = h8(Bx.c[kk]);
        C0 = mfma16(A0[kk], b, C0);
        C1 = mfma16(A1[kk], b, C1);
    }
}
// input layer burst: K=32, 4 MFMA
DEV void mfma_in4(const half8* I, const Frags& Bx, const f32x16& Z, f32x16& C0, f32x16& C1) {
    C0 = mfma16(I[0], h8(Bx.c[0]), Z);
    C1 = mfma16(I[2], h8(Bx.c[0]), Z);
    C0 = mfma16(I[1], h8(Bx.c[1]), C0);
    C1 = mfma16(I[3], h8(Bx.c[1]), C1);
}
// out layer burst: 4 MFMA, C-init = bias fragment bo
DEV void mfma_out4(const half8* Ao, const Frags& Bx, const f32x16& bo, f32x16& C) {
    C = mfma16(Ao[0], h8(Bx.c[0]), bo);
#pragma unroll
    for (int kk = 1; kk < 4; ++kk) C = mfma16(Ao[kk], h8(Bx.c[kk]), C);
}

DEV void store_out(const f32x16& C, int h, float* __restrict__ out, int row) {
    float* o = out + row * 21;
#pragma unroll
    for (int r = 0; r < 16; ++r) {
        int f = (r & 3) + 8 * (r >> 2) + 4 * h;
        if (f < 21) o[f] = __builtin_amdgcn_rcpf(1.f + __expf(-C[r]));
    }
}

DEV void load_x(const float* __restrict__ x, int row, int h, Frags& B) {
    // k = 16*kk + 8*h + e; x row stride 28 f32; k=28 slot carries 1.0 (bias rides in wI row 28)
    const float* xr = x + row * 28;
    float4 fa = *(const float4*)(xr + 8 * h);
    float4 fb = *(const float4*)(xr + 8 * h + 4);
    float4 fc = *(const float4*)(xr + 16 + 8 * h);
    float4 fd = (h == 0) ? *(const float4*)(xr + 20) : make_float4(1.f, 0.f, 0.f, 0.f);
    int4v c0, c1;
    c0[0] = pkrtz(fa.x, fa.y); c0[1] = pkrtz(fa.z, fa.w);
    c0[2] = pkrtz(fb.x, fb.y); c0[3] = pkrtz(fb.z, fb.w);
    c1[0] = pkrtz(fc.x, fc.y); c1[1] = pkrtz(fc.z, fc.w);
    c1[2] = pkrtz(fd.x, fd.y); c1[3] = pkrtz(fd.z, fd.w);
    B.c[0] = c0; B.c[1] = c1;
}

#define NT 512

__global__ __attribute__((amdgpu_flat_work_group_size(NT, NT), amdgpu_waves_per_eu(2, 2)))
void mlp_fused(
    const float* __restrict__ x, const float* __restrict__ W_in, const float* __restrict__ b_in,
    const float* __restrict__ W_hid, const float* __restrict__ b_hid,
    const float* __restrict__ W_out, const float* __restrict__ b_out,
    float* __restrict__ out) {
    // LDS weights in f16, A-fragment order: wH [l][m][kk 0..3][lam][e] (no bias chunk)
    __shared__ __align__(16) _Float16 wH[40960];     // 10 x 2 x 4 x 64 x 8 = 80 KB
    __shared__ __align__(16) _Float16 wI[2048];      // 2 x 2 x 64 x 8 (K=32, b_in in k=28)
    __shared__ __align__(16) _Float16 wO[2048];      // 4 x 64 x 8 (features 0..20)
    __shared__ __align__(16) _Float16 biasPkH[640];  // [l][m][h][q] packed f16x2 pairs
    __shared__ __align__(16) float biasOut[32];      // b_out in D-layout [h][r]

    const int tid = threadIdx.x;

    // zero phase: wI, wO (partially-filled buffers)
    for (int i = tid; i < 2048; i += NT) { wI[i] = (_Float16)0.f; wO[i] = (_Float16)0.f; }
    __syncthreads();

    // fill phase (coalesced global reads, scattered LDS writes)
    for (int i = tid; i < 40960; i += NT) {   // W_hid [l][kin][o]
        int o = i & 63, kin = (i >> 6) & 63, l = i >> 12;
        int m = o >> 5, kk = kin >> 4, hh = (kin >> 3) & 1, e = kin & 7;
        int lam = hh * 32 + (o & 31);
        wH[l * 4096 + m * 2048 + kk * 512 + lam * 8 + e] = (_Float16)W_hid[i];
    }
    for (int i = tid; i < 640; i += NT) {     // b_hid -> packed f16x2 D-layout pairs
        int u = i >> 1, j = i & 1;
        int l = u >> 5, rem = u & 31, m = rem >> 4, hh = (rem >> 3) & 1, q = rem & 7;
        int rr = 2 * q + j;
        int f = (rr & 3) + 8 * (rr >> 2) + 4 * hh + 32 * m;
        biasPkH[u * 2 + j] = (_Float16)b_hid[l * 64 + f];
    }
    for (int i = tid; i < 1792; i += NT) {    // W_in [28][64]
        int o = i & 63, kin = i >> 6;
        int m = o >> 5, kk = kin >> 4, hh = (kin >> 3) & 1, e = kin & 7;
        int lam = hh * 32 + (o & 31);
        wI[m * 1024 + kk * 512 + lam * 8 + e] = (_Float16)W_in[i];
    }
    for (int i = tid; i < 64; i += NT) {      // b_in -> wI k=28 slot: kk=1, hh=1, e=4
        int m = i >> 5;
        wI[m * 1024 + 512 + (32 + (i & 31)) * 8 + 4] = (_Float16)b_in[i];
    }
    for (int i = tid; i < 1344; i += NT) {    // W_out [64][21]
        int o = i % 21, kin = i / 21;
        int kk = kin >> 4, hh = (kin >> 3) & 1, e = kin & 7;
        int lam = hh * 32 + o;
        wO[kk * 512 + lam * 8 + e] = (_Float16)W_out[i];
    }
    for (int i = tid; i < 32; i += NT) {      // b_out D-layout [h][r]
        int hh = i >> 4, r = i & 15;
        int f = (r & 3) + 8 * (r >> 2) + 4 * hh;
        biasOut[i] = (f < 21) ? b_out[f] : 0.f;
    }
    __syncthreads();

    const int w = tid >> 6, lam = tid & 63;
    const int col = lam & 31, h = lam >> 5;
    const int* biasPk = (const int*)biasPkH;

    // hoisted invariants: out-layer A-frags, out bias fragment, persistent zero acc
    half8 Ao[4];
    {
        const _Float16* po = wO + lam * 8;
#pragma unroll
        for (int kk = 0; kk < 4; ++kk) Ao[kk] = ldh8(po + kk * 512);
    }
    f32x16 bo;
    {
        float4 b0 = *(const float4*)(biasOut + h * 16);
        float4 b1 = *(const float4*)(biasOut + h * 16 + 4);
        float4 b2 = *(const float4*)(biasOut + h * 16 + 8);
        float4 b3 = *(const float4*)(biasOut + h * 16 + 12);
        bo[0]=b0.x; bo[1]=b0.y; bo[2]=b0.z; bo[3]=b0.w;
        bo[4]=b1.x; bo[5]=b1.y; bo[6]=b1.z; bo[7]=b1.w;
        bo[8]=b2.x; bo[9]=b2.y; bo[10]=b2.z; bo[11]=b2.w;
        bo[12]=b3.x; bo[13]=b3.y; bo[14]=b3.z; bo[15]=b3.w;
    }
    f32x16 Z;
#pragma unroll
    for (int r = 0; r < 16; ++r) Z[r] = 0.f;

    // persistent: 256 blocks x 128 tiles; wave w owns tiles [w*16, w*16+16), 2 per iteration
    const int tbase = blockIdx.x * 128;
#pragma unroll 1
    for (int j = 0; j < 8; ++j) {
        int tA = tbase + w * 16 + 2 * j;
        int rowA = tA * 32 + col, rowB = rowA + 32;
        Frags BA, BB;
        load_x(x, rowA, h, BA);
        load_x(x, rowB, h, BB);
        half8 I[4];
        {
            const _Float16* p0 = wI + lam * 8;
            const _Float16* p1 = wI + 1024 + lam * 8;
            I[0] = ldh8(p0); I[1] = ldh8(p0 + 512);
            I[2] = ldh8(p1); I[3] = ldh8(p1 + 512);
        }

        half8 Fa0[4], Fa1[4], Fb0[4], Fb1[4];
        int4v Ba[4], Bb[4];
        f32x16 CA0, CA1, CB0, CB1;

        // ---- two-stream skewed pipeline ----
        mfma_in4(I, BA, Z, CA0, CA1);           // A burst (4 MFMA)
        loadA4(wH, lam, Fa0, Fa1);              // frags l=0 under A's burst
        mfma_in4(I, BB, Z, CB0, CB1);           // B burst
        loadBias(biasPk, 0, h, Ba);             // bias l=0 under B's burst
        repack_nb(CA0, CA1, BA);                // A repack (input: no bias add)

#pragma unroll
        for (int l2 = 0; l2 < 5; ++l2) {
            const _Float16* base = wH + (2 * l2) * 4096;
            // layer 2*l2 (frags Fa, bias Ba)
            mfma_hid8(Fa0, Fa1, BA, Z, CA0, CA1);       // A burst (8 MFMA)
            loadA4(base + 4096, lam, Fb0, Fb1);         // prefetch frags l+1
            if (l2 == 0) repack_nb(CB0, CB1, BB);       // B repack of input layer
            else         repack_b(CB0, CB1, Bb, BB);    // B repack of layer 2*l2-1
            mfma_hid8(Fa0, Fa1, BB, Z, CB0, CB1);       // B burst
            loadBias(biasPk, 2 * l2 + 1, h, Bb);        // prefetch bias l+1
            repack_b(CA0, CA1, Ba, BA);                 // A repack of layer 2*l2
            // layer 2*l2+1 (frags Fb, bias Bb)
            mfma_hid8(Fb0, Fb1, BA, Z, CA0, CA1);       // A burst
            if (l2 < 4) loadA4(base + 8192, lam, Fa0, Fa1);   // prefetch frags l+2
            repack_b(CB0, CB1, Ba, BB);                 // B repack of layer 2*l2
            mfma_hid8(Fb0, Fb1, BB, Z, CB0, CB1);       // B burst
            if (l2 < 4) loadBias(biasPk, 2 * l2 + 2, h, Ba);  // prefetch bias l+2
            repack_b(CA0, CA1, Bb, BA);                 // A repack of layer 2*l2+1
        }

        // out layer (C-init = bo, 4 MFMA)
        f32x16 CoA, CoB;
        mfma_out4(Ao, BA, bo, CoA);             // A burst
        repack_b(CB0, CB1, Bb, BB);             // B repack of layer 9
        mfma_out4(Ao, BB, bo, CoB);             // B burst
        store_out(CoA, h, out, rowA);           // A sigmoid+store under B's burst
        store_out(CoB, h, out, rowB);
    }
}

extern "C" void kernel_launch(void* const* d_in, const int* in_sizes, int n_in,
                              void* d_out, int out_size, void* d_ws, size_t ws_size,
                              hipStream_t stream) {
    const float* x     = (const float*)d_in[0];
    const float* W_in  = (const float*)d_in[1];
    const float* b_in  = (const float*)d_in[2];
    const float* W_hid = (const float*)d_in[3];
    const float* b_hid = (const float*)d_in[4];
    const float* W_out = (const float*)d_in[5];
    const float* b_out = (const float*)d_in[6];
    float* out = (float*)d_out;
    mlp_fused<<<dim3(256), dim3(NT), 0, stream>>>(x, W_in, b_in, W_hid, b_hid, W_out, b_out, out);
}